// Round 17
// baseline (9355.540 us; speedup 1.0000x reference)
//
#include <hip/hip_runtime.h>
#include <hip/hip_bf16.h>
#include <math.h>

#define HIDN 400
#define KK   10
#define UU   64
#define DD   60
#define TT   600
#define FCIN 800
#define FCOUT 121

#define NH1  100      // h1 blocks (4 units each, both batch-groups interleaved)
#define NH2  100      // h2 blocks (4 units each, full batch)
#define NWBK 32       // window blocks (2 batches each)
#define WBAT 2
#define TOTB 232
#define THR  1024
#define NWAVE 16
#define CB   16       // gate-cols per block (4 units x 4 gates)
#define PSTR 68       // h2 PART row stride (64 batches + pad)
#define PSTR2 36      // h1 PART row stride (32 batches + pad)

#define SLOT1 25600   // 400*64
#define SLOTW 3840    // 60*64

// ---- d_out offsets (floats) ----
#define PI_OFF    0
#define MU_OFF    768000
#define SIG_OFF   2304000
#define RHO_OFF   3840000
#define EOS_OFF   4608000
#define WF_OFF    4646400
#define KAPPA_OFF 4650240
#define PHI_OFF   4650880
#define H0F_OFF   4654976
#define C0F_OFF   4680576
#define H1F_OFF   4706176
#define C1F_OFF   4731776

// ---- workspace offsets (floats) ----
#define WS_H1T   0                  // 601*25600
#define WS_H2T   15385600           // 601*25600
#define WS_WHT   30771200           // 601*3840
#define WS_XST   33079040           // 600*3*64
#define WS_WALL1 33194240           // 100*463*16
#define WS_WALL2 33935040           // 100*863*16
#define WS_WFCT  35315840           // 800*121
#define WS_CNT   35412640           // 5504 ints
// total ~= 35,418,144 floats = 141.7 MB

// ---- grouped barrier counters (mod-8 ring, monotone), per batch-group ----
#define CAI(grp,i,g) ((((grp)*8 + ((i)&7))*13 + (g))*16)          // h1: 2x8x13 lines
#define CWI(grp,i,g) (3328 + (((grp)*8 + ((i)&7))*2 + (g))*16)    // w : 2x8x2 lines
#define CHI(i,g)     (3840 + (((i)&7)*13 + (g))*16)               // h2: 8x13 lines
#define CNT_INTS 5504

#define SMEM_F 32512   // 130 KB -> 1 block/CU

__device__ __forceinline__ float sigm(float x){ return 1.0f/(1.0f + expf(-x)); }
__device__ __forceinline__ int tgtn(int i, int n){ return n*((i>>3)+1); }

__device__ __forceinline__ void st_agent(float* p, float v){
  __hip_atomic_store(p, v, __ATOMIC_RELAXED, __HIP_MEMORY_SCOPE_AGENT);
}
__device__ __forceinline__ int ld_agent_i(const int* p){
  return __hip_atomic_load(p, __ATOMIC_RELAXED, __HIP_MEMORY_SCOPE_AGENT);
}
__device__ __forceinline__ void arrive(int* p){
  __hip_atomic_fetch_add(p, 1, __ATOMIC_RELAXED, __HIP_MEMORY_SCOPE_AGENT);
}
__device__ __forceinline__ void spin_ge(const int* w, int tgt){
  if (ld_agent_i(w) >= tgt) return;
  do { __builtin_amdgcn_s_sleep(1); } while (ld_agent_i(w) < tgt);
}

// ---------- prep ----------
__global__ void prep_init(const float* __restrict__ onehots, const float* __restrict__ strokes,
                          float* __restrict__ H1t, float* __restrict__ H2t,
                          float* __restrict__ Wh,  float* __restrict__ XST,
                          int* __restrict__ cnts){
  int idx = blockIdx.x*blockDim.x + threadIdx.x;
  if (idx < SLOT1){ H1t[idx] = 0.f; H2t[idx] = 0.f; }
  if (idx < SLOTW){
    int d = idx >> 6, b = idx & 63;
    Wh[idx] = onehots[b*(UU*DD) + d];            // onehots[b, u=0, d]
  }
  if (idx < TT*3*64){
    int t = idx/192, rem = idx%192, comp = rem/64, b = rem%64;
    XST[idx] = strokes[(b*TT + t)*3 + comp];
  }
  if (idx < CNT_INTS) cnts[idx] = 0;
}

// ---------- weight reorder: block owns units {4p..4p+3}; col c = 4*q + (j&3) ----------
// WALL1 rows: [0,400)=h1, [400,460)=w, [460,463)=x
// WALL2 rows: [0,400)=h1, [400,800)=h2, [800,860)=w, [860,863)=x
__global__ void prep_wall(const float* __restrict__ Wih1, const float* __restrict__ Whh1,
                          const float* __restrict__ Wih2, const float* __restrict__ Whh2,
                          float* __restrict__ WALL1, float* __restrict__ WALL2){
  int idx = blockIdx.x*blockDim.x + threadIdx.x;
  if (idx < 640000){                       // W_hh1 (1600,400)
    int g = idx/400, k = idx%400;
    int q = g/400, j = g%400, pp = j>>2, c = 4*q + (j&3);
    WALL1[((size_t)pp*463 + k)*CB + c] = Whh1[idx];
  } else if (idx < 740800){                // W_ih1 (1600,63)
    int s = idx - 640000;
    int g = s/63, col = s%63;
    int q = g/400, j = g%400, pp = j>>2, c = 4*q + (j&3);
    int r = (col < 3) ? (460 + col) : (400 + col - 3);
    WALL1[((size_t)pp*463 + r)*CB + c] = Wih1[s];
  } else if (idx < 1380800){               // W_hh2 (1600,400)
    int s = idx - 740800;
    int g = s/400, k = s%400;
    int q = g/400, j = g%400, pp = j>>2, c = 4*q + (j&3);
    WALL2[((size_t)pp*863 + 400 + k)*CB + c] = Whh2[s];
  } else if (idx < 2121600){               // W_ih2 (1600,463)
    int s = idx - 1380800;
    int g = s/463, col = s%463;
    int q = g/400, j = g%400, pp = j>>2, c = 4*q + (j&3);
    int r = (col<3) ? (860+col) : (col<63 ? (800+col-3) : (col-63));
    WALL2[((size_t)pp*863 + r)*CB + c] = Wih2[s];
  }
}

__global__ void prep_wfc(const float* __restrict__ Wfc, float* __restrict__ WfcT){
  int idx = blockIdx.x*blockDim.x + threadIdx.x;
  if (idx >= FCIN*FCOUT) return;
  int k = idx / FCOUT, j = idx - k*FCOUT;
  WfcT[idx] = Wfc[j*FCIN + k];
}

// ---------- GEMV segments ----------
__device__ __forceinline__ void gemv16(const float* __restrict__ x,
                                       const float* __restrict__ w,
                                       int n, int bg4, int cg4, float acc[16]){
  #pragma unroll 4
  for (int k=0;k<n;++k){
    const float4 xv = *(const float4*)(x + k*64 + bg4);
    const float4 wv = *(const float4*)(w + k*CB + cg4);
    acc[0]  = fmaf(wv.x, xv.x, acc[0]);
    acc[1]  = fmaf(wv.x, xv.y, acc[1]);
    acc[2]  = fmaf(wv.x, xv.z, acc[2]);
    acc[3]  = fmaf(wv.x, xv.w, acc[3]);
    acc[4]  = fmaf(wv.y, xv.x, acc[4]);
    acc[5]  = fmaf(wv.y, xv.y, acc[5]);
    acc[6]  = fmaf(wv.y, xv.z, acc[6]);
    acc[7]  = fmaf(wv.y, xv.w, acc[7]);
    acc[8]  = fmaf(wv.z, xv.x, acc[8]);
    acc[9]  = fmaf(wv.z, xv.y, acc[9]);
    acc[10] = fmaf(wv.z, xv.z, acc[10]);
    acc[11] = fmaf(wv.z, xv.w, acc[11]);
    acc[12] = fmaf(wv.w, xv.x, acc[12]);
    acc[13] = fmaf(wv.w, xv.y, acc[13]);
    acc[14] = fmaf(wv.w, xv.z, acc[14]);
    acc[15] = fmaf(wv.w, xv.w, acc[15]);
  }
}
// half-batch: 4 batches x 2 cols per lane
__device__ __forceinline__ void gemv8(const float* __restrict__ x,
                                      const float* __restrict__ w,
                                      int n, int bg4, int cg2, float acc[8]){
  #pragma unroll 4
  for (int k=0;k<n;++k){
    const float4 xv = *(const float4*)(x + k*64 + bg4);
    const float2 wv = *(const float2*)(w + k*CB + cg2);
    acc[0] = fmaf(wv.x, xv.x, acc[0]);
    acc[1] = fmaf(wv.x, xv.y, acc[1]);
    acc[2] = fmaf(wv.x, xv.z, acc[2]);
    acc[3] = fmaf(wv.x, xv.w, acc[3]);
    acc[4] = fmaf(wv.y, xv.x, acc[4]);
    acc[5] = fmaf(wv.y, xv.y, acc[5]);
    acc[6] = fmaf(wv.y, xv.z, acc[6]);
    acc[7] = fmaf(wv.y, xv.w, acc[7]);
  }
}

// ---------- persistent recurrent kernel ----------
__global__ __launch_bounds__(THR) void recurrent_kernel(
    const float* __restrict__ Wwin, const float* __restrict__ bwin,
    const float* __restrict__ b1g,  const float* __restrict__ b2g,
    const float* __restrict__ tmask,const float* __restrict__ onehots,
    const float* __restrict__ WALL1,const float* __restrict__ WALL2,
    float* __restrict__ H1t,        float* __restrict__ H2t,
    float* __restrict__ Wh,         const float* __restrict__ XST,
    int* __restrict__ cnts,         float* __restrict__ outp)
{
  const int p   = blockIdx.x;
  const int tid = threadIdx.x;
  __shared__ float SM[SMEM_F];

  if (p < NH1){
    // ===== H1 BLOCK (units 4p..4p+3), two batch-groups interleaved =====
    const int wave = tid >> 6, lane = tid & 63;
    const int bg4  = (lane & 7) * 4;    // 4 of 32 batches
    const int cg2  = (lane >> 3) * 2;   // 2 of 16 cols
    float* WL1 = SM;          float* PART = SM + 7408;    // [16][16][36] = 9216
    float* GRED= SM + 16624;  float* CS   = SM + 17136;   // GRED 512, CS 256 (2 grp)
    float* BS  = SM + 17392;

    for (int idx = tid; idx < 463*CB; idx += THR) WL1[idx] = WALL1[(size_t)p*463*CB + idx];
    if (tid < 16){ int q = tid>>2, u = tid&3; BS[tid] = b1g[q*HIDN + 4*p + u]; }
    if (tid < 256) CS[tid] = 0.f;
    __syncthreads();

    for (int j = 0; j < 2*TT; ++j){
      const int grp = j & 1, i = j >> 1;
      const int gb  = grp * 32;
      // detect CA_grp(i-1): published 2 half-iters ago -> normally pre-satisfied
      if (i >= 1){
        if (tid < 13) spin_ge(&cnts[CAI(grp, i-1, tid)], tgtn(i-1, tid==12?4:8));
        asm volatile("" ::: "memory");
        __syncthreads();
      }
      float acc[8] = {0,0,0,0,0,0,0,0};
      // A: h1_grp(i-1) rows [0,400) + x(i) rows
      {
        const float* __restrict__ H1prev = H1t + (size_t)i*SLOT1 + gb;
        int k0 = wave*26, k1 = min(k0 + 26, 403);
        { int ka = k0, kb = min(k1, 400);
          if (kb > ka) gemv8(H1prev + ka*64, WL1 + ka*CB, kb-ka, bg4, cg2, acc); }
        { int ka = max(k0,400), kb = k1;
          if (kb > ka) gemv8(XST + i*192 + (ka-400)*64 + gb, WL1 + (460+(ka-400))*CB, kb-ka, bg4, cg2, acc); }
      }
      // reduce A-part
      *(float4*)&PART[(wave*16 + cg2  )*PSTR2 + bg4] = make_float4(acc[0],acc[1],acc[2],acc[3]);
      *(float4*)&PART[(wave*16 + cg2+1)*PSTR2 + bg4] = make_float4(acc[4],acc[5],acc[6],acc[7]);
      __syncthreads();
      if (tid < 512){
        int c = tid>>5, b = tid&31; float s = 0.f;
        #pragma unroll
        for (int w16=0; w16<NWAVE; ++w16) s += PART[(w16*16 + c)*PSTR2 + b];
        GRED[c*32 + b] = s;
      }
      __syncthreads();
      // wait w_grp(i-1)
      if (i >= 1){
        if (tid < 2) spin_ge(&cnts[CWI(grp, i-1, tid)], tgtn(i-1, 8));
        asm volatile("" ::: "memory");
        __syncthreads();
      }
      // pointwise with inline w-GEMV
      if (tid < 128){
        int u = tid>>5, b = tid&31, jj = 4*p + u;
        float gi = GRED[( 0+u)*32+b] + BS[ 0+u];
        float gf = GRED[( 4+u)*32+b] + BS[ 4+u];
        float gg = GRED[( 8+u)*32+b] + BS[ 8+u];
        float go = GRED[(12+u)*32+b] + BS[12+u];
        const float* __restrict__ Whp = Wh + (size_t)i*SLOTW + gb + b;
        const float* __restrict__ Ww  = WL1 + 400*CB + u;
        #pragma unroll 4
        for (int d = 0; d < DD; ++d){
          float wv = Whp[d*64];
          gi = fmaf(wv, Ww[d*CB     ], gi);
          gf = fmaf(wv, Ww[d*CB +  4], gf);
          gg = fmaf(wv, Ww[d*CB +  8], gg);
          go = fmaf(wv, Ww[d*CB + 12], go);
        }
        float* cs = &CS[grp*128 + u*32 + b];
        float c_ = sigm(gf)*(*cs) + sigm(gi)*tanhf(gg);
        float h_ = sigm(go)*tanhf(c_);
        *cs = c_;
        st_agent(&H1t[(size_t)(i+1)*SLOT1 + jj*64 + gb + b], h_);
        if (i == TT-1){ outp[H0F_OFF + (gb+b)*HIDN + jj] = h_; outp[C0F_OFF + (gb+b)*HIDN + jj] = c_; }
      }
      __syncthreads();                       // drain publish
      if (tid == 0) arrive(&cnts[CAI(grp, i, p>>3)]);
    }
  } else if (p < NH1 + NH2){
    // ===== H2 BLOCK (units 4q2..4q2+3), full batch =====
    const int q2 = p - NH1;
    const int wave = tid >> 6, lane = tid & 63;
    const int bg4  = (lane & 15) * 4;
    const int cg4  = (lane >> 4) * 4;
    float* WL2 = SM;          float* PART = SM + 13808;
    float* GRED= SM + 31216;  float* CS   = SM + 32240;
    float* BS  = SM + 32496;

    for (int idx = tid; idx < 863*CB; idx += THR) WL2[idx] = WALL2[(size_t)q2*863*CB + idx];
    if (tid < 16){ int q = tid>>2, u = tid&3; BS[tid] = b2g[q*HIDN + 4*q2 + u]; }
    if (tid < 256) CS[tid] = 0.f;
    __syncthreads();

    for (int t2 = 0; t2 < TT; ++t2){
      // wait h1(t2) both groups, w(t2) both groups — lagging pipeline
      if (tid < 13)                      spin_ge(&cnts[CAI(0, t2, tid)],    tgtn(t2, tid==12?4:8));
      else if (tid >= 64 && tid < 77)    spin_ge(&cnts[CAI(1, t2, tid-64)], tgtn(t2, (tid-64)==12?4:8));
      else if (tid >= 128 && tid < 132){ int g=(tid-128)>>1, l=(tid-128)&1;
                                         spin_ge(&cnts[CWI(g, t2, l)],      tgtn(t2, 8)); }
      asm volatile("" ::: "memory");
      __syncthreads();
      float acc[16];
      #pragma unroll
      for (int z=0; z<16; ++z) acc[z] = 0.f;
      // A: h1(t2) [0,400), w(t2) [800,860), x(t2) [860,863)
      {
        const float* __restrict__ H1v = H1t + (size_t)(t2+1)*SLOT1;
        const float* __restrict__ Whv = Wh  + (size_t)(t2+1)*SLOTW;
        int k0 = wave*29, k1 = min(k0 + 29, 463);
        { int ka = k0, kb = min(k1, 400);
          if (kb > ka) gemv16(H1v + ka*64, WL2 + ka*CB, kb-ka, bg4, cg4, acc); }
        { int ka = max(k0,400), kb = min(k1, 460);
          if (kb > ka) gemv16(Whv + (ka-400)*64, WL2 + (800+(ka-400))*CB, kb-ka, bg4, cg4, acc); }
        { int ka = max(k0,460), kb = k1;
          if (kb > ka) gemv16(XST + t2*192 + (ka-460)*64, WL2 + (860+(ka-460))*CB, kb-ka, bg4, cg4, acc); }
      }
      // own chain: h2(t2-1)
      if (t2 >= 1){
        if (tid < 13) spin_ge(&cnts[CHI(t2-1, tid)], tgtn(t2-1, tid==12?4:8));
        asm volatile("" ::: "memory");
        __syncthreads();
      }
      // B: h2(t2-1) rows [400,800)
      {
        const float* __restrict__ H2v = H2t + (size_t)t2*SLOT1;
        int k0 = wave*25, k1 = min(k0 + 25, 400);
        if (k1 > k0) gemv16(H2v + k0*64, WL2 + (400+k0)*CB, k1-k0, bg4, cg4, acc);
      }
      // reduce + pointwise + publish h2(t2)
      #pragma unroll
      for (int cc=0; cc<4; ++cc)
        *(float4*)&PART[(wave*16 + cg4 + cc)*PSTR + bg4] =
          make_float4(acc[cc*4+0], acc[cc*4+1], acc[cc*4+2], acc[cc*4+3]);
      __syncthreads();
      {
        int c = tid>>6, b = tid&63; float s = 0.f;
        #pragma unroll
        for (int w16=0; w16<NWAVE; ++w16) s += PART[(w16*16 + c)*PSTR + b];
        GRED[c*64 + b] = s;
      }
      __syncthreads();
      if (tid < 256){
        int u = tid>>6, b = tid&63, jj = 4*q2 + u;
        float gi = GRED[( 0+u)*64+b] + BS[ 0+u];
        float gf = GRED[( 4+u)*64+b] + BS[ 4+u];
        float gg = GRED[( 8+u)*64+b] + BS[ 8+u];
        float go = GRED[(12+u)*64+b] + BS[12+u];
        float c_ = sigm(gf)*CS[u*64+b] + sigm(gi)*tanhf(gg);
        float h_ = sigm(go)*tanhf(c_);
        CS[u*64+b] = c_;
        st_agent(&H2t[(size_t)(t2+1)*SLOT1 + jj*64 + b], h_);
        if (t2 == TT-1){ outp[H1F_OFF + b*HIDN + jj] = h_; outp[C1F_OFF + b*HIDN + jj] = c_; }
      }
      __syncthreads();                       // drain publish
      if (tid == 0) arrive(&cnts[CHI(t2, q2>>3)]);
    }
  } else {
    // ===== WINDOW BLOCK (2 batches, one batch-group) =====
    const int wb = p - NH1 - NH2;
    const int b0 = wb * WBAT;                // absolute batch
    const int grp = wb >> 4;                 // batches 0-31 -> grp0, 32-63 -> grp1
    float* WWT = SM;          float* ONE = SM + 13200;
    float* H1S = SM + 20880;  float* TMS = SM + 22080;
    float* PW  = SM + 22208;  float* KAP = SM + 22272;
    float* PHI = SM + 22304;

    for (int idx = tid; idx < 30*400; idx += THR){
      int jj = idx/400, k = idx - jj*400;
      WWT[k*33 + jj] = Wwin[idx];
    }
    for (int idx = tid; idx < WBAT*UU*DD; idx += THR) ONE[idx] = onehots[b0*(UU*DD) + idx];
    if (tid < WBAT*UU) TMS[tid] = tmask[b0*UU + tid];
    if (tid < WBAT*16) KAP[tid] = 0.f;
    __syncthreads();

    for (int i = 0; i < TT; ++i){
      if (tid < 13) spin_ge(&cnts[CAI(grp, i, tid)], tgtn(i, tid==12?4:8));
      asm volatile("" ::: "memory");
      __syncthreads();
      const float* __restrict__ H1now = H1t + (size_t)(i+1)*SLOT1;
      if (tid < 400){
        float2 v = *(const float2*)&H1now[tid*64 + b0];
        H1S[tid*3 + 0] = v.x;
        H1S[tid*3 + 1] = v.y;
      }
      __syncthreads();
      if (tid < 960){
        int ks = tid & 15, pair = tid >> 4;
        int b = pair / 30, jj = pair - b*30;
        float s = 0.f;
        #pragma unroll
        for (int kk = 0; kk < 25; ++kk){
          int k = ks*25 + kk;
          s = fmaf(H1S[k*3 + b], WWT[k*33 + jj], s);
        }
        s += __shfl_down(s, 8, 16);
        s += __shfl_down(s, 4, 16);
        s += __shfl_down(s, 2, 16);
        s += __shfl_down(s, 1, 16);
        if (ks == 0) PW[b*32 + jj] = expf(s + bwin[jj]);
      }
      __syncthreads();
      if (tid < WBAT*KK){
        int b = tid/KK, k = tid - b*KK;
        KAP[b*16 + k] += PW[b*32 + 20 + k];
      }
      __syncthreads();
      if (tid < WBAT*UU){
        int b = tid >> 6, u = tid & 63;
        float uf = (float)u, s = 0.f;
        #pragma unroll
        for (int q = 0; q < KK; ++q){
          float d = KAP[b*16 + q] - uf;
          s = fmaf(PW[b*32 + q], expf(-PW[b*32 + 10 + q]*d*d), s);
        }
        s *= TMS[b*64 + u];
        PHI[b*64 + u] = s;
        if (i == TT-1) outp[PHI_OFF + (b0+b)*UU + u] = s;
      }
      __syncthreads();
      if (tid < WBAT*DD){
        int b = tid/DD, d = tid - b*DD;
        float s = 0.f;
        #pragma unroll 8
        for (int u = 0; u < UU; ++u) s = fmaf(PHI[b*64 + u], ONE[b*(UU*DD) + u*DD + d], s);
        st_agent(&Wh[(size_t)(i+1)*SLOTW + d*64 + b0 + b], s);  // publish w(i)
        if (i == TT-1) outp[WF_OFF + (b0+b)*DD + d] = s;
      }
      if (i == TT-1 && tid < WBAT*KK){
        int b = tid/KK, k = tid - b*KK;
        outp[KAPPA_OFF + (b0+b)*KK + k] = KAP[b*16 + k];
      }
      __syncthreads();                       // drain w publish
      if (tid == 0) arrive(&cnts[CWI(grp, i, (wb & 15) >> 3)]);
    }
  }
}

// ---------- FC + heads: one block per timestep ----------
__global__ __launch_bounds__(128) void fc2_kernel(
    const float* __restrict__ H1t, const float* __restrict__ H2t,
    const float* __restrict__ WfcT, const float* __restrict__ bfc,
    float* __restrict__ outp)
{
  const int t   = blockIdx.x;
  const int tid = threadIdx.x;
  __shared__ float Xs[8][64];
  __shared__ float OUT[FCOUT][65];
  float acc[64];
  #pragma unroll
  for (int b=0;b<64;++b) acc[b]=0.f;
  const float* __restrict__ base1 = H1t + (size_t)(t+1)*SLOT1;
  const float* __restrict__ base2 = H2t + (size_t)(t+1)*SLOT1;

  for (int kb=0; kb<100; ++kb){
    __syncthreads();
    #pragma unroll
    for (int e=0;e<4;++e){
      int idx = e*128 + tid;
      int row = idx>>6, b = idx&63;
      int k = kb*8 + row;
      Xs[row][b] = (k<400) ? base1[k*64+b] : base2[(k-400)*64+b];
    }
    __syncthreads();
    if (tid < FCOUT){
      #pragma unroll
      for (int kk=0;kk<8;++kk){
        float wv = WfcT[(kb*8+kk)*FCOUT + tid];
        #pragma unroll
        for (int b4=0;b4<16;++b4){
          float4 xv = *(const float4*)&Xs[kk][b4*4];
          acc[b4*4+0] = fmaf(wv, xv.x, acc[b4*4+0]);
          acc[b4*4+1] = fmaf(wv, xv.y, acc[b4*4+1]);
          acc[b4*4+2] = fmaf(wv, xv.z, acc[b4*4+2]);
          acc[b4*4+3] = fmaf(wv, xv.w, acc[b4*4+3]);
        }
      }
    }
  }
  if (tid < FCOUT){
    float bj = bfc[tid];
    #pragma unroll
    for (int b=0;b<64;++b) OUT[tid][b] = acc[b] + bj;
  }
  __syncthreads();
  if (tid < 64){
    const int b = tid;
    const size_t pos = (size_t)b*TT + t;
    for (int j=0;j<40;++j) outp[MU_OFF  + pos*40 + j] = OUT[j][b];
    for (int j=0;j<40;++j) outp[SIG_OFF + pos*40 + j] = OUT[40+j][b];
    float m = -1e30f;
    for (int q=0;q<20;++q) m = fmaxf(m, OUT[80+q][b]);
    float e[20], s=0.f;
    for (int q=0;q<20;++q){ e[q]=expf(OUT[80+q][b]-m); s+=e[q]; }
    float inv = 1.f/s;
    for (int q=0;q<20;++q) outp[PI_OFF  + pos*20 + q] = e[q]*inv;
    for (int q=0;q<20;++q) outp[RHO_OFF + pos*20 + q] = tanhf(OUT[100+q][b]);
    outp[EOS_OFF + pos] = 1.0f/(1.0f + expf(OUT[120][b]));
  }
}

extern "C" void kernel_launch(void* const* d_in, const int* in_sizes, int n_in,
                              void* d_out, int out_size, void* d_ws, size_t ws_size,
                              hipStream_t stream){
  (void)in_sizes; (void)n_in; (void)out_size; (void)ws_size;
  const float* strokes = (const float*)d_in[0];
  const float* onehots = (const float*)d_in[1];
  const float* tmask   = (const float*)d_in[2];
  const float* Wih1    = (const float*)d_in[3];
  const float* Whh1    = (const float*)d_in[4];
  const float* b1      = (const float*)d_in[5];
  const float* Wwin    = (const float*)d_in[6];
  const float* bwin    = (const float*)d_in[7];
  const float* Wih2    = (const float*)d_in[8];
  const float* Whh2    = (const float*)d_in[9];
  const float* b2      = (const float*)d_in[10];
  const float* Wfc     = (const float*)d_in[11];
  const float* bfc     = (const float*)d_in[12];

  float* ws    = (float*)d_ws;
  float* outp  = (float*)d_out;
  float* H1t   = ws + WS_H1T;
  float* H2t   = ws + WS_H2T;
  float* Wh    = ws + WS_WHT;
  float* XST   = ws + WS_XST;
  float* WALL1 = ws + WS_WALL1;
  float* WALL2 = ws + WS_WALL2;
  float* WfcT  = ws + WS_WFCT;
  int*   cnts  = (int*)(ws + WS_CNT);

  hipLaunchKernelGGL(prep_init, dim3((TT*3*64 + 255)/256), dim3(256), 0, stream,
                     onehots, strokes, H1t, H2t, Wh, XST, cnts);
  hipLaunchKernelGGL(prep_wall, dim3((2121600 + 255)/256), dim3(256), 0, stream,
                     Wih1, Whh1, Wih2, Whh2, WALL1, WALL2);
  hipLaunchKernelGGL(prep_wfc, dim3((FCIN*FCOUT + 255)/256), dim3(256), 0, stream,
                     Wfc, WfcT);

  hipLaunchKernelGGL(recurrent_kernel, dim3(TOTB), dim3(THR), 0, stream,
                     Wwin, bwin, b1, b2, tmask, onehots, WALL1, WALL2,
                     H1t, H2t, Wh, XST, cnts, outp);

  hipLaunchKernelGGL(fc2_kernel, dim3(TT), dim3(128), 0, stream,
                     H1t, H2t, WfcT, bfc, outp);
}

// Round 18
// 8871.837 us; speedup vs baseline: 1.0545x; 1.0545x over previous
//
#include <hip/hip_runtime.h>
#include <hip/hip_bf16.h>
#include <math.h>

#define HIDN 400
#define KK   10
#define UU   64
#define DD   60
#define TT   600
#define FCIN 800
#define FCOUT 121

#define NH1  100      // h1 blocks (4 units each)
#define NH2  100      // h2 blocks (4 units each)
#define NWBK 32       // window blocks (2 batches each)
#define WBAT 2
#define TOTB 232
#define THR  1024
#define NWAVE 16
#define CB   16       // gate-cols per block (4 units x 4 gates)
#define PSTR 68       // padded PART row stride

#define SLOT1 25600   // 400*64
#define SLOTW 3840    // 60*64

// ---- d_out offsets (floats) ----
#define PI_OFF    0
#define MU_OFF    768000
#define SIG_OFF   2304000
#define RHO_OFF   3840000
#define EOS_OFF   4608000
#define WF_OFF    4646400
#define KAPPA_OFF 4650240
#define PHI_OFF   4650880
#define H0F_OFF   4654976
#define C0F_OFF   4680576
#define H1F_OFF   4706176
#define C1F_OFF   4731776

// ---- workspace offsets (floats) ----
#define WS_H1T   0                  // 601*25600
#define WS_H2T   15385600           // 601*25600
#define WS_WHT   30771200           // 601*3840
#define WS_XST   33079040           // 600*3*64
#define WS_WALL1 33194240           // 100*463*16
#define WS_WALL2 33935040           // 100*863*16
#define WS_WFCT  35315840           // 800*121
#define WS_CNT   35412640           // 3840 ints
// total ~= 35,416,480 floats = 141.7 MB

// ---- grouped barrier counters (mod-8 ring, monotone) ----
#define CAI(i,g) ((((i)&7)*13+(g))*16)            // h1: 13 groups (12x8 + 1x4 blocks)
#define CWI(i,g) (1664 + (((i)&7)*4+(g))*16)      // w : 4 groups of 8
#define CHI(i,g) (2176 + (((i)&7)*13+(g))*16)     // h2: 13 groups
#define CNT_INTS 3840

#define SMEM_F 32512   // 130 KB -> 1 block/CU

__device__ __forceinline__ float sigm(float x){ return 1.0f/(1.0f + expf(-x)); }
__device__ __forceinline__ int tgtn(int i, int n){ return n*((i>>3)+1); }

__device__ __forceinline__ void st_agent(float* p, float v){
  __hip_atomic_store(p, v, __ATOMIC_RELAXED, __HIP_MEMORY_SCOPE_AGENT);
}
__device__ __forceinline__ int ld_agent_i(const int* p){
  return __hip_atomic_load(p, __ATOMIC_RELAXED, __HIP_MEMORY_SCOPE_AGENT);
}
__device__ __forceinline__ void arrive(int* p){
  __hip_atomic_fetch_add(p, 1, __ATOMIC_RELAXED, __HIP_MEMORY_SCOPE_AGENT);
}
__device__ __forceinline__ void spin_ge(const int* w, int tgt){
  if (ld_agent_i(w) >= tgt) return;
  do { __builtin_amdgcn_s_sleep(1); } while (ld_agent_i(w) < tgt);
}

// ---------- prep ----------
__global__ void prep_init(const float* __restrict__ onehots, const float* __restrict__ strokes,
                          float* __restrict__ H1t, float* __restrict__ H2t,
                          float* __restrict__ Wh,  float* __restrict__ XST,
                          int* __restrict__ cnts){
  int idx = blockIdx.x*blockDim.x + threadIdx.x;
  if (idx < SLOT1){ H1t[idx] = 0.f; H2t[idx] = 0.f; }
  if (idx < SLOTW){
    int d = idx >> 6, b = idx & 63;
    Wh[idx] = onehots[b*(UU*DD) + d];            // onehots[b, u=0, d]
  }
  if (idx < TT*3*64){
    int t = idx/192, rem = idx%192, comp = rem/64, b = rem%64;
    XST[idx] = strokes[(b*TT + t)*3 + comp];
  }
  if (idx < CNT_INTS) cnts[idx] = 0;
}

// ---------- weight reorder: block owns units {4p..4p+3}; col c = 4*q + (j&3) ----------
// WALL1 rows: [0,400)=h1, [400,460)=w, [460,463)=x
// WALL2 rows: [0,400)=h1, [400,800)=h2, [800,860)=w, [860,863)=x
__global__ void prep_wall(const float* __restrict__ Wih1, const float* __restrict__ Whh1,
                          const float* __restrict__ Wih2, const float* __restrict__ Whh2,
                          float* __restrict__ WALL1, float* __restrict__ WALL2){
  int idx = blockIdx.x*blockDim.x + threadIdx.x;
  if (idx < 640000){                       // W_hh1 (1600,400)
    int g = idx/400, k = idx%400;
    int q = g/400, j = g%400, pp = j>>2, c = 4*q + (j&3);
    WALL1[((size_t)pp*463 + k)*CB + c] = Whh1[idx];
  } else if (idx < 740800){                // W_ih1 (1600,63)
    int s = idx - 640000;
    int g = s/63, col = s%63;
    int q = g/400, j = g%400, pp = j>>2, c = 4*q + (j&3);
    int r = (col < 3) ? (460 + col) : (400 + col - 3);
    WALL1[((size_t)pp*463 + r)*CB + c] = Wih1[s];
  } else if (idx < 1380800){               // W_hh2 (1600,400)
    int s = idx - 740800;
    int g = s/400, k = s%400;
    int q = g/400, j = g%400, pp = j>>2, c = 4*q + (j&3);
    WALL2[((size_t)pp*863 + 400 + k)*CB + c] = Whh2[s];
  } else if (idx < 2121600){               // W_ih2 (1600,463)
    int s = idx - 1380800;
    int g = s/463, col = s%463;
    int q = g/400, j = g%400, pp = j>>2, c = 4*q + (j&3);
    int r = (col<3) ? (860+col) : (col<63 ? (800+col-3) : (col-63));
    WALL2[((size_t)pp*863 + r)*CB + c] = Wih2[s];
  }
}

__global__ void prep_wfc(const float* __restrict__ Wfc, float* __restrict__ WfcT){
  int idx = blockIdx.x*blockDim.x + threadIdx.x;
  if (idx >= FCIN*FCOUT) return;
  int k = idx / FCOUT, j = idx - k*FCOUT;
  WfcT[idx] = Wfc[j*FCIN + k];
}

// ---------- GEMV segment: 16 cols ----------
__device__ __forceinline__ void gemv16(const float* __restrict__ x,
                                       const float* __restrict__ w,
                                       int n, int bg4, int cg4, float acc[16]){
  #pragma unroll 4
  for (int k=0;k<n;++k){
    const float4 xv = *(const float4*)(x + k*64 + bg4);
    const float4 wv = *(const float4*)(w + k*CB + cg4);
    acc[0]  = fmaf(wv.x, xv.x, acc[0]);
    acc[1]  = fmaf(wv.x, xv.y, acc[1]);
    acc[2]  = fmaf(wv.x, xv.z, acc[2]);
    acc[3]  = fmaf(wv.x, xv.w, acc[3]);
    acc[4]  = fmaf(wv.y, xv.x, acc[4]);
    acc[5]  = fmaf(wv.y, xv.y, acc[5]);
    acc[6]  = fmaf(wv.y, xv.z, acc[6]);
    acc[7]  = fmaf(wv.y, xv.w, acc[7]);
    acc[8]  = fmaf(wv.z, xv.x, acc[8]);
    acc[9]  = fmaf(wv.z, xv.y, acc[9]);
    acc[10] = fmaf(wv.z, xv.z, acc[10]);
    acc[11] = fmaf(wv.z, xv.w, acc[11]);
    acc[12] = fmaf(wv.w, xv.x, acc[12]);
    acc[13] = fmaf(wv.w, xv.y, acc[13]);
    acc[14] = fmaf(wv.w, xv.z, acc[14]);
    acc[15] = fmaf(wv.w, xv.w, acc[15]);
  }
}

// ---------- persistent recurrent kernel ----------
__global__ __launch_bounds__(THR) void recurrent_kernel(
    const float* __restrict__ Wwin, const float* __restrict__ bwin,
    const float* __restrict__ b1g,  const float* __restrict__ b2g,
    const float* __restrict__ tmask,const float* __restrict__ onehots,
    const float* __restrict__ WALL1,const float* __restrict__ WALL2,
    float* __restrict__ H1t,        float* __restrict__ H2t,
    float* __restrict__ Wh,         const float* __restrict__ XST,
    int* __restrict__ cnts,         float* __restrict__ outp)
{
  const int p   = blockIdx.x;
  const int tid = threadIdx.x;
  __shared__ float SM[SMEM_F];

  if (p < NH1){
    // ================= H1 BLOCK (units 4p..4p+3) =================
    const int wave = tid >> 6, lane = tid & 63;
    const int bg4  = (lane & 15) * 4;
    const int cg4  = (lane >> 4) * 4;
    float* WL1 = SM;          float* PART = SM + 7408;
    float* GRED= SM + 24816;  float* CS   = SM + 25840;
    float* BS  = SM + 26096;

    for (int idx = tid; idx < 463*CB; idx += THR) WL1[idx] = WALL1[(size_t)p*463*CB + idx];
    if (tid < 16){ int q = tid>>2, u = tid&3; BS[tid] = b1g[q*HIDN + 4*p + u]; }
    if (tid < 256) CS[tid] = 0.f;
    __syncthreads();

    for (int i = 0; i < TT; ++i){
      if (i >= 1){
        if (tid < 13) spin_ge(&cnts[CAI(i-1, tid)], tgtn(i-1, tid==12?4:8));
        asm volatile("" ::: "memory");
        __syncthreads();
      }
      float acc[16];
      #pragma unroll
      for (int z=0; z<16; ++z) acc[z] = 0.f;
      // A: h1(i-1) rows [0,400) + x(i) rows (WL1 460..462)
      {
        const float* __restrict__ H1prev = H1t + (size_t)i*SLOT1;
        int k0 = wave*26, k1 = min(k0 + 26, 403);
        { int ka = k0, kb = min(k1, 400);
          if (kb > ka) gemv16(H1prev + ka*64, WL1 + ka*CB, kb-ka, bg4, cg4, acc); }
        { int ka = max(k0,400), kb = k1;
          if (kb > ka) gemv16(XST + i*192 + (ka-400)*64, WL1 + (460+(ka-400))*CB, kb-ka, bg4, cg4, acc); }
      }
      // reduce A-part
      #pragma unroll
      for (int cc=0; cc<4; ++cc)
        *(float4*)&PART[(wave*16 + cg4 + cc)*PSTR + bg4] =
          make_float4(acc[cc*4+0], acc[cc*4+1], acc[cc*4+2], acc[cc*4+3]);
      __syncthreads();
      {
        int c = tid>>6, b = tid&63; float s = 0.f;
        #pragma unroll
        for (int w16=0; w16<NWAVE; ++w16) s += PART[(w16*16 + c)*PSTR + b];
        GRED[c*64 + b] = s;
      }
      __syncthreads();
      // wait w(i-1) — window had the whole A+reduce time to produce it
      if (i >= 1){
        if (tid < 4) spin_ge(&cnts[CWI(i-1, tid)], tgtn(i-1, 8));
        asm volatile("" ::: "memory");
        __syncthreads();
      }
      // pointwise with inline w-GEMV: gates[c][b] += sum_d w[d][b]*W1w[d][c]
      if (tid < 256){
        int u = tid>>6, b = tid&63, j = 4*p + u;
        float gi = GRED[( 0+u)*64+b] + BS[ 0+u];
        float gf = GRED[( 4+u)*64+b] + BS[ 4+u];
        float gg = GRED[( 8+u)*64+b] + BS[ 8+u];
        float go = GRED[(12+u)*64+b] + BS[12+u];
        const float* __restrict__ Whp = Wh + (size_t)i*SLOTW + b;
        const float* __restrict__ Ww  = WL1 + 400*CB + u;
        #pragma unroll 4
        for (int d = 0; d < DD; ++d){
          float wv = Whp[d*64];
          gi = fmaf(wv, Ww[d*CB     ], gi);
          gf = fmaf(wv, Ww[d*CB +  4], gf);
          gg = fmaf(wv, Ww[d*CB +  8], gg);
          go = fmaf(wv, Ww[d*CB + 12], go);
        }
        float c_ = sigm(gf)*CS[u*64+b] + sigm(gi)*tanhf(gg);
        float h_ = sigm(go)*tanhf(c_);
        CS[u*64+b] = c_;
        st_agent(&H1t[(size_t)(i+1)*SLOT1 + j*64 + b], h_);
        if (i == TT-1){ outp[H0F_OFF + b*HIDN + j] = h_; outp[C0F_OFF + b*HIDN + j] = c_; }
      }
      __syncthreads();                       // drain publish
      if (tid == 0) arrive(&cnts[CAI(i, p>>3)]);
    }
  } else if (p < NH1 + NH2){
    // ================= H2 BLOCK (units 4q2..4q2+3) =================
    const int q2 = p - NH1;
    const int wave = tid >> 6, lane = tid & 63;
    const int bg4  = (lane & 15) * 4;
    const int cg4  = (lane >> 4) * 4;
    float* WL2 = SM;          float* PART = SM + 13808;
    float* GRED= SM + 31216;  float* CS   = SM + 32240;
    float* BS  = SM + 32496;

    for (int idx = tid; idx < 863*CB; idx += THR) WL2[idx] = WALL2[(size_t)q2*863*CB + idx];
    if (tid < 16){ int q = tid>>2, u = tid&3; BS[tid] = b2g[q*HIDN + 4*q2 + u]; }
    if (tid < 256) CS[tid] = 0.f;
    __syncthreads();

    for (int t2 = 0; t2 < TT; ++t2){
      // wait h1(t2), w(t2) — lagging pipeline, usually pre-satisfied
      if (tid < 13) spin_ge(&cnts[CAI(t2, tid)], tgtn(t2, tid==12?4:8));
      else if (tid >= 64 && tid < 68) spin_ge(&cnts[CWI(t2, tid-64)], tgtn(t2, 8));
      asm volatile("" ::: "memory");
      __syncthreads();
      float acc[16];
      #pragma unroll
      for (int z=0; z<16; ++z) acc[z] = 0.f;
      // A: h1(t2) [0,400), w(t2) [800,860), x(t2) [860,863)
      {
        const float* __restrict__ H1v = H1t + (size_t)(t2+1)*SLOT1;
        const float* __restrict__ Whv = Wh  + (size_t)(t2+1)*SLOTW;
        int k0 = wave*29, k1 = min(k0 + 29, 463);
        { int ka = k0, kb = min(k1, 400);
          if (kb > ka) gemv16(H1v + ka*64, WL2 + ka*CB, kb-ka, bg4, cg4, acc); }
        { int ka = max(k0,400), kb = min(k1, 460);
          if (kb > ka) gemv16(Whv + (ka-400)*64, WL2 + (800+(ka-400))*CB, kb-ka, bg4, cg4, acc); }
        { int ka = max(k0,460), kb = k1;
          if (kb > ka) gemv16(XST + t2*192 + (ka-460)*64, WL2 + (860+(ka-460))*CB, kb-ka, bg4, cg4, acc); }
      }
      // own chain: h2(t2-1)
      if (t2 >= 1){
        if (tid < 13) spin_ge(&cnts[CHI(t2-1, tid)], tgtn(t2-1, tid==12?4:8));
        asm volatile("" ::: "memory");
        __syncthreads();
      }
      // B: h2(t2-1) rows [400,800)
      {
        const float* __restrict__ H2v = H2t + (size_t)t2*SLOT1;
        int k0 = wave*25, k1 = min(k0 + 25, 400);
        if (k1 > k0) gemv16(H2v + k0*64, WL2 + (400+k0)*CB, k1-k0, bg4, cg4, acc);
      }
      // reduce + pointwise + publish h2(t2)
      #pragma unroll
      for (int cc=0; cc<4; ++cc)
        *(float4*)&PART[(wave*16 + cg4 + cc)*PSTR + bg4] =
          make_float4(acc[cc*4+0], acc[cc*4+1], acc[cc*4+2], acc[cc*4+3]);
      __syncthreads();
      {
        int c = tid>>6, b = tid&63; float s = 0.f;
        #pragma unroll
        for (int w16=0; w16<NWAVE; ++w16) s += PART[(w16*16 + c)*PSTR + b];
        GRED[c*64 + b] = s;
      }
      __syncthreads();
      if (tid < 256){
        int u = tid>>6, b = tid&63, j = 4*q2 + u;
        float gi = GRED[( 0+u)*64+b] + BS[ 0+u];
        float gf = GRED[( 4+u)*64+b] + BS[ 4+u];
        float gg = GRED[( 8+u)*64+b] + BS[ 8+u];
        float go = GRED[(12+u)*64+b] + BS[12+u];
        float c_ = sigm(gf)*CS[u*64+b] + sigm(gi)*tanhf(gg);
        float h_ = sigm(go)*tanhf(c_);
        CS[u*64+b] = c_;
        st_agent(&H2t[(size_t)(t2+1)*SLOT1 + j*64 + b], h_);
        if (t2 == TT-1){ outp[H1F_OFF + b*HIDN + j] = h_; outp[C1F_OFF + b*HIDN + j] = c_; }
      }
      __syncthreads();                       // drain publish
      if (tid == 0) arrive(&cnts[CHI(t2, q2>>3)]);
    }
  } else {
    // ================= WINDOW BLOCK (2 batches), per-wave pipelined dots =================
    const int wb = p - NH1 - NH2;
    const int b0 = wb * WBAT;
    const int wave = tid >> 6, lane = tid & 63;
    float* WWT  = SM;           // 13200: Wwin^T [400][33]
    float* ONE  = SM + 13200;   // 7680
    float* PARTW= SM + 20880;   // 832: [13][64] partial dots
    float* TMS  = SM + 21712;   // 128
    float* PW   = SM + 21840;   // 64
    float* KAP  = SM + 21904;   // 32
    float* PHI  = SM + 21936;   // 128

    for (int idx = tid; idx < 30*400; idx += THR){
      int j = idx/400, k = idx - j*400;
      WWT[k*33 + j] = Wwin[idx];
    }
    for (int idx = tid; idx < WBAT*UU*DD; idx += THR) ONE[idx] = onehots[b0*(UU*DD) + idx];
    if (tid < WBAT*UU) TMS[tid] = tmask[b0*UU + tid];
    if (tid < WBAT*16) KAP[tid] = 0.f;
    __syncthreads();

    for (int i = 0; i < TT; ++i){
      const float* __restrict__ H1now = H1t + (size_t)(i+1)*SLOT1;
      // wave g: spin on arrival group g, then partial dot over its 32 rows
      if (wave < 13){
        if (lane == 0) spin_ge(&cnts[CAI(i, wave)], tgtn(i, wave==12?4:8));
        asm volatile("" ::: "memory");
        const int base = wave*32;
        const int b = lane >> 5, jj = lane & 31;
        float s = 0.f;
        if (jj < 30){
          if (wave == 12){
            #pragma unroll
            for (int kk = 0; kk < 16; ++kk){
              int k = base + kk;
              s = fmaf(H1now[k*64 + b0 + b], WWT[k*33 + jj], s);
            }
          } else {
            #pragma unroll
            for (int kk = 0; kk < 32; ++kk){
              int k = base + kk;
              s = fmaf(H1now[k*64 + b0 + b], WWT[k*33 + jj], s);
            }
          }
        }
        PARTW[wave*64 + lane] = s;
      }
      __syncthreads();
      // final reduce over 13 groups + exp
      if (tid < 64){
        int b = tid >> 5, jj = tid & 31;
        if (jj < 30){
          float s = 0.f;
          #pragma unroll
          for (int g = 0; g < 13; ++g) s += PARTW[g*64 + tid];
          PW[b*32 + jj] = expf(s + bwin[jj]);
        }
      }
      __syncthreads();
      if (tid < WBAT*KK){
        int b = tid/KK, k = tid - b*KK;
        KAP[b*16 + k] += PW[b*32 + 20 + k];
      }
      __syncthreads();
      if (tid < WBAT*UU){
        int b = tid >> 6, u = tid & 63;
        float uf = (float)u, s = 0.f;
        #pragma unroll
        for (int q = 0; q < KK; ++q){
          float d = KAP[b*16 + q] - uf;
          s = fmaf(PW[b*32 + q], expf(-PW[b*32 + 10 + q]*d*d), s);
        }
        s *= TMS[b*64 + u];
        PHI[b*64 + u] = s;
        if (i == TT-1) outp[PHI_OFF + (b0+b)*UU + u] = s;
      }
      __syncthreads();
      if (tid < WBAT*DD){
        int b = tid/DD, d = tid - b*DD;
        float s = 0.f;
        #pragma unroll 8
        for (int u = 0; u < UU; ++u) s = fmaf(PHI[b*64 + u], ONE[b*(UU*DD) + u*DD + d], s);
        st_agent(&Wh[(size_t)(i+1)*SLOTW + d*64 + b0 + b], s);  // publish w(i)
        if (i == TT-1) outp[WF_OFF + (b0+b)*DD + d] = s;
      }
      if (i == TT-1 && tid < WBAT*KK){
        int b = tid/KK, k = tid - b*KK;
        outp[KAPPA_OFF + (b0+b)*KK + k] = KAP[b*16 + k];
      }
      __syncthreads();                       // drain w publish
      if (tid == 0) arrive(&cnts[CWI(i, wb>>3)]);
    }
  }
}

// ---------- FC + heads: one block per timestep ----------
__global__ __launch_bounds__(128) void fc2_kernel(
    const float* __restrict__ H1t, const float* __restrict__ H2t,
    const float* __restrict__ WfcT, const float* __restrict__ bfc,
    float* __restrict__ outp)
{
  const int t   = blockIdx.x;
  const int tid = threadIdx.x;
  __shared__ float Xs[8][64];
  __shared__ float OUT[FCOUT][65];
  float acc[64];
  #pragma unroll
  for (int b=0;b<64;++b) acc[b]=0.f;
  const float* __restrict__ base1 = H1t + (size_t)(t+1)*SLOT1;
  const float* __restrict__ base2 = H2t + (size_t)(t+1)*SLOT1;

  for (int kb=0; kb<100; ++kb){
    __syncthreads();
    #pragma unroll
    for (int e=0;e<4;++e){
      int idx = e*128 + tid;
      int row = idx>>6, b = idx&63;
      int k = kb*8 + row;
      Xs[row][b] = (k<400) ? base1[k*64+b] : base2[(k-400)*64+b];
    }
    __syncthreads();
    if (tid < FCOUT){
      #pragma unroll
      for (int kk=0;kk<8;++kk){
        float wv = WfcT[(kb*8+kk)*FCOUT + tid];
        #pragma unroll
        for (int b4=0;b4<16;++b4){
          float4 xv = *(const float4*)&Xs[kk][b4*4];
          acc[b4*4+0] = fmaf(wv, xv.x, acc[b4*4+0]);
          acc[b4*4+1] = fmaf(wv, xv.y, acc[b4*4+1]);
          acc[b4*4+2] = fmaf(wv, xv.z, acc[b4*4+2]);
          acc[b4*4+3] = fmaf(wv, xv.w, acc[b4*4+3]);
        }
      }
    }
  }
  if (tid < FCOUT){
    float bj = bfc[tid];
    #pragma unroll
    for (int b=0;b<64;++b) OUT[tid][b] = acc[b] + bj;
  }
  __syncthreads();
  if (tid < 64){
    const int b = tid;
    const size_t pos = (size_t)b*TT + t;
    for (int j=0;j<40;++j) outp[MU_OFF  + pos*40 + j] = OUT[j][b];
    for (int j=0;j<40;++j) outp[SIG_OFF + pos*40 + j] = OUT[40+j][b];
    float m = -1e30f;
    for (int q=0;q<20;++q) m = fmaxf(m, OUT[80+q][b]);
    float e[20], s=0.f;
    for (int q=0;q<20;++q){ e[q]=expf(OUT[80+q][b]-m); s+=e[q]; }
    float inv = 1.f/s;
    for (int q=0;q<20;++q) outp[PI_OFF  + pos*20 + q] = e[q]*inv;
    for (int q=0;q<20;++q) outp[RHO_OFF + pos*20 + q] = tanhf(OUT[100+q][b]);
    outp[EOS_OFF + pos] = 1.0f/(1.0f + expf(OUT[120][b]));
  }
}

extern "C" void kernel_launch(void* const* d_in, const int* in_sizes, int n_in,
                              void* d_out, int out_size, void* d_ws, size_t ws_size,
                              hipStream_t stream){
  (void)in_sizes; (void)n_in; (void)out_size; (void)ws_size;
  const float* strokes = (const float*)d_in[0];
  const float* onehots = (const float*)d_in[1];
  const float* tmask   = (const float*)d_in[2];
  const float* Wih1    = (const float*)d_in[3];
  const float* Whh1    = (const float*)d_in[4];
  const float* b1      = (const float*)d_in[5];
  const float* Wwin    = (const float*)d_in[6];
  const float* bwin    = (const float*)d_in[7];
  const float* Wih2    = (const float*)d_in[8];
  const float* Whh2    = (const float*)d_in[9];
  const float* b2      = (const float*)d_in[10];
  const float* Wfc     = (const float*)d_in[11];
  const float* bfc     = (const float*)d_in[12];

  float* ws    = (float*)d_ws;
  float* outp  = (float*)d_out;
  float* H1t   = ws + WS_H1T;
  float* H2t   = ws + WS_H2T;
  float* Wh    = ws + WS_WHT;
  float* XST   = ws + WS_XST;
  float* WALL1 = ws + WS_WALL1;
  float* WALL2 = ws + WS_WALL2;
  float* WfcT  = ws + WS_WFCT;
  int*   cnts  = (int*)(ws + WS_CNT);

  hipLaunchKernelGGL(prep_init, dim3((TT*3*64 + 255)/256), dim3(256), 0, stream,
                     onehots, strokes, H1t, H2t, Wh, XST, cnts);
  hipLaunchKernelGGL(prep_wall, dim3((2121600 + 255)/256), dim3(256), 0, stream,
                     Wih1, Whh1, Wih2, Whh2, WALL1, WALL2);
  hipLaunchKernelGGL(prep_wfc, dim3((FCIN*FCOUT + 255)/256), dim3(256), 0, stream,
                     Wfc, WfcT);

  hipLaunchKernelGGL(recurrent_kernel, dim3(TOTB), dim3(THR), 0, stream,
                     Wwin, bwin, b1, b2, tmask, onehots, WALL1, WALL2,
                     H1t, H2t, Wh, XST, cnts, outp);

  hipLaunchKernelGGL(fc2_kernel, dim3(TT), dim3(128), 0, stream,
                     H1t, H2t, WfcT, bfc, outp);
}

// Round 19
// 6547.913 us; speedup vs baseline: 1.4288x; 1.3549x over previous
//
#include <hip/hip_runtime.h>
#include <hip/hip_bf16.h>
#include <math.h>

#define HIDN 400
#define KK   10
#define UU   64
#define DD   60
#define TT   600
#define FCIN 800
#define FCOUT 121

#define NH1  100      // h1 blocks (4 units each)
#define NH2  100      // h2 blocks (4 units each)
#define NWBK 32       // window blocks (2 batches each)
#define WBAT 2
#define TOTB 232
#define THR  1024
#define NWAVE 16
#define CB   16       // gate-cols per block (4 units x 4 gates)
#define PSTR 68       // padded PART row stride

#define SLOT1 25600   // 400*64
#define SLOTW 3840    // 60*64

// ---- d_out offsets (floats) ----
#define PI_OFF    0
#define MU_OFF    768000
#define SIG_OFF   2304000
#define RHO_OFF   3840000
#define EOS_OFF   4608000
#define WF_OFF    4646400
#define KAPPA_OFF 4650240
#define PHI_OFF   4650880
#define H0F_OFF   4654976
#define C0F_OFF   4680576
#define H1F_OFF   4706176
#define C1F_OFF   4731776

// ---- workspace offsets (floats) ----
#define WS_H1T   0                  // 601*25600
#define WS_H2T   15385600           // 601*25600
#define WS_WHT   30771200           // 601*3840
#define WS_XST   33079040           // 600*3*64
#define WS_WALL1 33194240           // 100*463*16
#define WS_WALL2 33935040           // 100*863*16
#define WS_WFCT  35315840           // 800*121
#define WS_CNT   35412640           // 3840 ints
// total ~= 35,416,480 floats = 141.7 MB

// ---- grouped barrier counters (mod-8 ring, monotone) ----
#define CAI(i,g) ((((i)&7)*13+(g))*16)            // h1: 13 groups (12x8 + 1x4 blocks)
#define CWI(i,g) (1664 + (((i)&7)*4+(g))*16)      // w : 4 groups of 8
#define CHI(i,g) (2176 + (((i)&7)*13+(g))*16)     // h2: 13 groups
#define CNT_INTS 3840

#define SMEM_F 32512   // 130 KB -> 1 block/CU

__device__ __forceinline__ float sigm(float x){ return 1.0f/(1.0f + expf(-x)); }
__device__ __forceinline__ int tgtn(int i, int n){ return n*((i>>3)+1); }

__device__ __forceinline__ void st_agent(float* p, float v){
  __hip_atomic_store(p, v, __ATOMIC_RELAXED, __HIP_MEMORY_SCOPE_AGENT);
}
__device__ __forceinline__ int ld_agent_i(const int* p){
  return __hip_atomic_load(p, __ATOMIC_RELAXED, __HIP_MEMORY_SCOPE_AGENT);
}
__device__ __forceinline__ void arrive(int* p){
  __hip_atomic_fetch_add(p, 1, __ATOMIC_RELAXED, __HIP_MEMORY_SCOPE_AGENT);
}
__device__ __forceinline__ void spin_ge(const int* w, int tgt){
  if (ld_agent_i(w) >= tgt) return;
  do { __builtin_amdgcn_s_sleep(1); } while (ld_agent_i(w) < tgt);
}

// ---------- prep ----------
__global__ void prep_init(const float* __restrict__ onehots, const float* __restrict__ strokes,
                          float* __restrict__ H1t, float* __restrict__ H2t,
                          float* __restrict__ Wh,  float* __restrict__ XST,
                          int* __restrict__ cnts){
  int idx = blockIdx.x*blockDim.x + threadIdx.x;
  if (idx < SLOT1){ H1t[idx] = 0.f; H2t[idx] = 0.f; }
  if (idx < SLOTW){
    int d = idx >> 6, b = idx & 63;
    Wh[idx] = onehots[b*(UU*DD) + d];            // onehots[b, u=0, d]
  }
  if (idx < TT*3*64){
    int t = idx/192, rem = idx%192, comp = rem/64, b = rem%64;
    XST[idx] = strokes[(b*TT + t)*3 + comp];
  }
  if (idx < CNT_INTS) cnts[idx] = 0;
}

// ---------- weight reorder: block owns units {4p..4p+3}; col c = 4*q + (j&3) ----------
// WALL1 rows: [0,400)=h1, [400,460)=w, [460,463)=x
// WALL2 rows: [0,400)=h1, [400,800)=h2, [800,860)=w, [860,863)=x
__global__ void prep_wall(const float* __restrict__ Wih1, const float* __restrict__ Whh1,
                          const float* __restrict__ Wih2, const float* __restrict__ Whh2,
                          float* __restrict__ WALL1, float* __restrict__ WALL2){
  int idx = blockIdx.x*blockDim.x + threadIdx.x;
  if (idx < 640000){                       // W_hh1 (1600,400)
    int g = idx/400, k = idx%400;
    int q = g/400, j = g%400, pp = j>>2, c = 4*q + (j&3);
    WALL1[((size_t)pp*463 + k)*CB + c] = Whh1[idx];
  } else if (idx < 740800){                // W_ih1 (1600,63)
    int s = idx - 640000;
    int g = s/63, col = s%63;
    int q = g/400, j = g%400, pp = j>>2, c = 4*q + (j&3);
    int r = (col < 3) ? (460 + col) : (400 + col - 3);
    WALL1[((size_t)pp*463 + r)*CB + c] = Wih1[s];
  } else if (idx < 1380800){               // W_hh2 (1600,400)
    int s = idx - 740800;
    int g = s/400, k = s%400;
    int q = g/400, j = g%400, pp = j>>2, c = 4*q + (j&3);
    WALL2[((size_t)pp*863 + 400 + k)*CB + c] = Whh2[s];
  } else if (idx < 2121600){               // W_ih2 (1600,463)
    int s = idx - 1380800;
    int g = s/463, col = s%463;
    int q = g/400, j = g%400, pp = j>>2, c = 4*q + (j&3);
    int r = (col<3) ? (860+col) : (col<63 ? (800+col-3) : (col-63));
    WALL2[((size_t)pp*863 + r)*CB + c] = Wih2[s];
  }
}

__global__ void prep_wfc(const float* __restrict__ Wfc, float* __restrict__ WfcT){
  int idx = blockIdx.x*blockDim.x + threadIdx.x;
  if (idx >= FCIN*FCOUT) return;
  int k = idx / FCOUT, j = idx - k*FCOUT;
  WfcT[idx] = Wfc[j*FCIN + k];
}

// ---------- GEMV segment: 16 cols ----------
__device__ __forceinline__ void gemv16(const float* __restrict__ x,
                                       const float* __restrict__ w,
                                       int n, int bg4, int cg4, float acc[16]){
  #pragma unroll 4
  for (int k=0;k<n;++k){
    const float4 xv = *(const float4*)(x + k*64 + bg4);
    const float4 wv = *(const float4*)(w + k*CB + cg4);
    acc[0]  = fmaf(wv.x, xv.x, acc[0]);
    acc[1]  = fmaf(wv.x, xv.y, acc[1]);
    acc[2]  = fmaf(wv.x, xv.z, acc[2]);
    acc[3]  = fmaf(wv.x, xv.w, acc[3]);
    acc[4]  = fmaf(wv.y, xv.x, acc[4]);
    acc[5]  = fmaf(wv.y, xv.y, acc[5]);
    acc[6]  = fmaf(wv.y, xv.z, acc[6]);
    acc[7]  = fmaf(wv.y, xv.w, acc[7]);
    acc[8]  = fmaf(wv.z, xv.x, acc[8]);
    acc[9]  = fmaf(wv.z, xv.y, acc[9]);
    acc[10] = fmaf(wv.z, xv.z, acc[10]);
    acc[11] = fmaf(wv.z, xv.w, acc[11]);
    acc[12] = fmaf(wv.w, xv.x, acc[12]);
    acc[13] = fmaf(wv.w, xv.y, acc[13]);
    acc[14] = fmaf(wv.w, xv.z, acc[14]);
    acc[15] = fmaf(wv.w, xv.w, acc[15]);
  }
}

// ---------- persistent recurrent kernel ----------
__global__ __launch_bounds__(THR) void recurrent_kernel(
    const float* __restrict__ Wwin, const float* __restrict__ bwin,
    const float* __restrict__ b1g,  const float* __restrict__ b2g,
    const float* __restrict__ tmask,const float* __restrict__ onehots,
    const float* __restrict__ WALL1,const float* __restrict__ WALL2,
    float* __restrict__ H1t,        float* __restrict__ H2t,
    float* __restrict__ Wh,         const float* __restrict__ XST,
    int* __restrict__ cnts,         float* __restrict__ outp)
{
  const int p   = blockIdx.x;
  const int tid = threadIdx.x;
  __shared__ float SM[SMEM_F];

  if (p < NH1){
    // ================= H1 BLOCK (units 4p..4p+3) =================
    const int wave = tid >> 6, lane = tid & 63;
    const int bg4  = (lane & 15) * 4;
    const int cg4  = (lane >> 4) * 4;
    float* WL1 = SM;          float* PART = SM + 7408;
    float* GRED= SM + 24816;  float* CS   = SM + 25840;
    float* BS  = SM + 26096;

    for (int idx = tid; idx < 463*CB; idx += THR) WL1[idx] = WALL1[(size_t)p*463*CB + idx];
    if (tid < 16){ int q = tid>>2, u = tid&3; BS[tid] = b1g[q*HIDN + 4*p + u]; }
    if (tid < 256) CS[tid] = 0.f;
    __syncthreads();

    for (int i = 0; i < TT; ++i){
      if (i >= 1){
        if (tid < 13) spin_ge(&cnts[CAI(i-1, tid)], tgtn(i-1, tid==12?4:8));
        asm volatile("" ::: "memory");
        __syncthreads();
      }
      float acc[16];
      #pragma unroll
      for (int z=0; z<16; ++z) acc[z] = 0.f;
      // A: h1(i-1) rows [0,400) + x(i) rows (WL1 460..462)
      {
        const float* __restrict__ H1prev = H1t + (size_t)i*SLOT1;
        int k0 = wave*26, k1 = min(k0 + 26, 403);
        { int ka = k0, kb = min(k1, 400);
          if (kb > ka) gemv16(H1prev + ka*64, WL1 + ka*CB, kb-ka, bg4, cg4, acc); }
        { int ka = max(k0,400), kb = k1;
          if (kb > ka) gemv16(XST + i*192 + (ka-400)*64, WL1 + (460+(ka-400))*CB, kb-ka, bg4, cg4, acc); }
      }
      // reduce A-part
      #pragma unroll
      for (int cc=0; cc<4; ++cc)
        *(float4*)&PART[(wave*16 + cg4 + cc)*PSTR + bg4] =
          make_float4(acc[cc*4+0], acc[cc*4+1], acc[cc*4+2], acc[cc*4+3]);
      __syncthreads();
      {
        int c = tid>>6, b = tid&63; float s = 0.f;
        #pragma unroll
        for (int w16=0; w16<NWAVE; ++w16) s += PART[(w16*16 + c)*PSTR + b];
        GRED[c*64 + b] = s;
      }
      __syncthreads();
      // wait w(i-1) — window had the whole A+reduce time to produce it
      if (i >= 1){
        if (tid < 4) spin_ge(&cnts[CWI(i-1, tid)], tgtn(i-1, 8));
        asm volatile("" ::: "memory");
        __syncthreads();
      }
      // pointwise with inline w-GEMV: gates[c][b] += sum_d w[d][b]*W1w[d][c]
      if (tid < 256){
        int u = tid>>6, b = tid&63, j = 4*p + u;
        float gi = GRED[( 0+u)*64+b] + BS[ 0+u];
        float gf = GRED[( 4+u)*64+b] + BS[ 4+u];
        float gg = GRED[( 8+u)*64+b] + BS[ 8+u];
        float go = GRED[(12+u)*64+b] + BS[12+u];
        const float* __restrict__ Whp = Wh + (size_t)i*SLOTW + b;
        const float* __restrict__ Ww  = WL1 + 400*CB + u;
        #pragma unroll 4
        for (int d = 0; d < DD; ++d){
          float wv = Whp[d*64];
          gi = fmaf(wv, Ww[d*CB     ], gi);
          gf = fmaf(wv, Ww[d*CB +  4], gf);
          gg = fmaf(wv, Ww[d*CB +  8], gg);
          go = fmaf(wv, Ww[d*CB + 12], go);
        }
        float c_ = sigm(gf)*CS[u*64+b] + sigm(gi)*tanhf(gg);
        float h_ = sigm(go)*tanhf(c_);
        CS[u*64+b] = c_;
        st_agent(&H1t[(size_t)(i+1)*SLOT1 + j*64 + b], h_);
        if (i == TT-1){ outp[H0F_OFF + b*HIDN + j] = h_; outp[C0F_OFF + b*HIDN + j] = c_; }
      }
      __syncthreads();                       // drain publish
      if (tid == 0) arrive(&cnts[CAI(i, p>>3)]);
    }
  } else if (p < NH1 + NH2){
    // ================= H2 BLOCK (units 4q2..4q2+3) =================
    const int q2 = p - NH1;
    const int wave = tid >> 6, lane = tid & 63;
    const int bg4  = (lane & 15) * 4;
    const int cg4  = (lane >> 4) * 4;
    float* WL2 = SM;          float* PART = SM + 13808;
    float* GRED= SM + 31216;  float* CS   = SM + 32240;
    float* BS  = SM + 32496;

    for (int idx = tid; idx < 863*CB; idx += THR) WL2[idx] = WALL2[(size_t)q2*863*CB + idx];
    if (tid < 16){ int q = tid>>2, u = tid&3; BS[tid] = b2g[q*HIDN + 4*q2 + u]; }
    if (tid < 256) CS[tid] = 0.f;
    __syncthreads();

    for (int t2 = 0; t2 < TT; ++t2){
      // wait h1(t2), w(t2) — lagging pipeline, usually pre-satisfied
      if (tid < 13) spin_ge(&cnts[CAI(t2, tid)], tgtn(t2, tid==12?4:8));
      else if (tid >= 64 && tid < 68) spin_ge(&cnts[CWI(t2, tid-64)], tgtn(t2, 8));
      asm volatile("" ::: "memory");
      __syncthreads();
      float acc[16];
      #pragma unroll
      for (int z=0; z<16; ++z) acc[z] = 0.f;
      // A: h1(t2) [0,400), w(t2) [800,860), x(t2) [860,863)
      {
        const float* __restrict__ H1v = H1t + (size_t)(t2+1)*SLOT1;
        const float* __restrict__ Whv = Wh  + (size_t)(t2+1)*SLOTW;
        int k0 = wave*29, k1 = min(k0 + 29, 463);
        { int ka = k0, kb = min(k1, 400);
          if (kb > ka) gemv16(H1v + ka*64, WL2 + ka*CB, kb-ka, bg4, cg4, acc); }
        { int ka = max(k0,400), kb = min(k1, 460);
          if (kb > ka) gemv16(Whv + (ka-400)*64, WL2 + (800+(ka-400))*CB, kb-ka, bg4, cg4, acc); }
        { int ka = max(k0,460), kb = k1;
          if (kb > ka) gemv16(XST + t2*192 + (ka-460)*64, WL2 + (860+(ka-460))*CB, kb-ka, bg4, cg4, acc); }
      }
      // own chain: h2(t2-1)
      if (t2 >= 1){
        if (tid < 13) spin_ge(&cnts[CHI(t2-1, tid)], tgtn(t2-1, tid==12?4:8));
        asm volatile("" ::: "memory");
        __syncthreads();
      }
      // B: h2(t2-1) rows [400,800)
      {
        const float* __restrict__ H2v = H2t + (size_t)t2*SLOT1;
        int k0 = wave*25, k1 = min(k0 + 25, 400);
        if (k1 > k0) gemv16(H2v + k0*64, WL2 + (400+k0)*CB, k1-k0, bg4, cg4, acc);
      }
      // reduce + pointwise + publish h2(t2)
      #pragma unroll
      for (int cc=0; cc<4; ++cc)
        *(float4*)&PART[(wave*16 + cg4 + cc)*PSTR + bg4] =
          make_float4(acc[cc*4+0], acc[cc*4+1], acc[cc*4+2], acc[cc*4+3]);
      __syncthreads();
      {
        int c = tid>>6, b = tid&63; float s = 0.f;
        #pragma unroll
        for (int w16=0; w16<NWAVE; ++w16) s += PART[(w16*16 + c)*PSTR + b];
        GRED[c*64 + b] = s;
      }
      __syncthreads();
      if (tid < 256){
        int u = tid>>6, b = tid&63, j = 4*q2 + u;
        float gi = GRED[( 0+u)*64+b] + BS[ 0+u];
        float gf = GRED[( 4+u)*64+b] + BS[ 4+u];
        float gg = GRED[( 8+u)*64+b] + BS[ 8+u];
        float go = GRED[(12+u)*64+b] + BS[12+u];
        float c_ = sigm(gf)*CS[u*64+b] + sigm(gi)*tanhf(gg);
        float h_ = sigm(go)*tanhf(c_);
        CS[u*64+b] = c_;
        st_agent(&H2t[(size_t)(t2+1)*SLOT1 + j*64 + b], h_);
        if (t2 == TT-1){ outp[H1F_OFF + b*HIDN + j] = h_; outp[C1F_OFF + b*HIDN + j] = c_; }
      }
      __syncthreads();                       // drain publish
      if (tid == 0) arrive(&cnts[CHI(t2, q2>>3)]);
    }
  } else {
    // ================= WINDOW BLOCK (2 batches) =================
    const int wb = p - NH1 - NH2;
    const int b0 = wb * WBAT;
    float* WWT = SM;          float* ONE = SM + 13200;
    float* H1S = SM + 20880;  float* TMS = SM + 22080;
    float* PW  = SM + 22208;  float* KAP = SM + 22272;
    float* PHI = SM + 22304;

    for (int idx = tid; idx < 30*400; idx += THR){
      int j = idx/400, k = idx - j*400;
      WWT[k*33 + j] = Wwin[idx];
    }
    for (int idx = tid; idx < WBAT*UU*DD; idx += THR) ONE[idx] = onehots[b0*(UU*DD) + idx];
    if (tid < WBAT*UU) TMS[tid] = tmask[b0*UU + tid];
    if (tid < WBAT*16) KAP[tid] = 0.f;
    __syncthreads();

    for (int i = 0; i < TT; ++i){
      if (tid < 13) spin_ge(&cnts[CAI(i, tid)], tgtn(i, tid==12?4:8));
      asm volatile("" ::: "memory");
      __syncthreads();
      const float* __restrict__ H1now = H1t + (size_t)(i+1)*SLOT1;
      if (tid < 400){
        float2 v = *(const float2*)&H1now[tid*64 + b0];
        H1S[tid*3 + 0] = v.x;
        H1S[tid*3 + 1] = v.y;
      }
      __syncthreads();
      if (tid < 960){
        int ks = tid & 15, pair = tid >> 4;
        int b = pair / 30, j = pair - b*30;
        float s = 0.f;
        #pragma unroll
        for (int kk = 0; kk < 25; ++kk){
          int k = ks*25 + kk;
          s = fmaf(H1S[k*3 + b], WWT[k*33 + j], s);
        }
        s += __shfl_down(s, 8, 16);
        s += __shfl_down(s, 4, 16);
        s += __shfl_down(s, 2, 16);
        s += __shfl_down(s, 1, 16);
        if (ks == 0) PW[b*32 + j] = expf(s + bwin[j]);
      }
      __syncthreads();
      if (tid < WBAT*KK){
        int b = tid/KK, k = tid - b*KK;
        KAP[b*16 + k] += PW[b*32 + 20 + k];
      }
      __syncthreads();
      if (tid < WBAT*UU){
        int b = tid >> 6, u = tid & 63;
        float uf = (float)u, s = 0.f;
        #pragma unroll
        for (int q = 0; q < KK; ++q){
          float d = KAP[b*16 + q] - uf;
          s = fmaf(PW[b*32 + q], expf(-PW[b*32 + 10 + q]*d*d), s);
        }
        s *= TMS[b*64 + u];
        PHI[b*64 + u] = s;
        if (i == TT-1) outp[PHI_OFF + (b0+b)*UU + u] = s;
      }
      __syncthreads();
      if (tid < WBAT*DD){
        int b = tid/DD, d = tid - b*DD;
        float s = 0.f;
        #pragma unroll 8
        for (int u = 0; u < UU; ++u) s = fmaf(PHI[b*64 + u], ONE[b*(UU*DD) + u*DD + d], s);
        st_agent(&Wh[(size_t)(i+1)*SLOTW + d*64 + b0 + b], s);  // publish w(i)
        if (i == TT-1) outp[WF_OFF + (b0+b)*DD + d] = s;
      }
      if (i == TT-1 && tid < WBAT*KK){
        int b = tid/KK, k = tid - b*KK;
        outp[KAPPA_OFF + (b0+b)*KK + k] = KAP[b*16 + k];
      }
      __syncthreads();                       // drain w publish
      if (tid == 0) arrive(&cnts[CWI(i, wb>>3)]);
    }
  }
}

// ---------- FC + heads: one block per timestep ----------
__global__ __launch_bounds__(128) void fc2_kernel(
    const float* __restrict__ H1t, const float* __restrict__ H2t,
    const float* __restrict__ WfcT, const float* __restrict__ bfc,
    float* __restrict__ outp)
{
  const int t   = blockIdx.x;
  const int tid = threadIdx.x;
  __shared__ float Xs[8][64];
  __shared__ float OUT[FCOUT][65];
  float acc[64];
  #pragma unroll
  for (int b=0;b<64;++b) acc[b]=0.f;
  const float* __restrict__ base1 = H1t + (size_t)(t+1)*SLOT1;
  const float* __restrict__ base2 = H2t + (size_t)(t+1)*SLOT1;

  for (int kb=0; kb<100; ++kb){
    __syncthreads();
    #pragma unroll
    for (int e=0;e<4;++e){
      int idx = e*128 + tid;
      int row = idx>>6, b = idx&63;
      int k = kb*8 + row;
      Xs[row][b] = (k<400) ? base1[k*64+b] : base2[(k-400)*64+b];
    }
    __syncthreads();
    if (tid < FCOUT){
      #pragma unroll
      for (int kk=0;kk<8;++kk){
        float wv = WfcT[(kb*8+kk)*FCOUT + tid];
        #pragma unroll
        for (int b4=0;b4<16;++b4){
          float4 xv = *(const float4*)&Xs[kk][b4*4];
          acc[b4*4+0] = fmaf(wv, xv.x, acc[b4*4+0]);
          acc[b4*4+1] = fmaf(wv, xv.y, acc[b4*4+1]);
          acc[b4*4+2] = fmaf(wv, xv.z, acc[b4*4+2]);
          acc[b4*4+3] = fmaf(wv, xv.w, acc[b4*4+3]);
        }
      }
    }
  }
  if (tid < FCOUT){
    float bj = bfc[tid];
    #pragma unroll
    for (int b=0;b<64;++b) OUT[tid][b] = acc[b] + bj;
  }
  __syncthreads();
  if (tid < 64){
    const int b = tid;
    const size_t pos = (size_t)b*TT + t;
    for (int j=0;j<40;++j) outp[MU_OFF  + pos*40 + j] = OUT[j][b];
    for (int j=0;j<40;++j) outp[SIG_OFF + pos*40 + j] = OUT[40+j][b];
    float m = -1e30f;
    for (int q=0;q<20;++q) m = fmaxf(m, OUT[80+q][b]);
    float e[20], s=0.f;
    for (int q=0;q<20;++q){ e[q]=expf(OUT[80+q][b]-m); s+=e[q]; }
    float inv = 1.f/s;
    for (int q=0;q<20;++q) outp[PI_OFF  + pos*20 + q] = e[q]*inv;
    for (int q=0;q<20;++q) outp[RHO_OFF + pos*20 + q] = tanhf(OUT[100+q][b]);
    outp[EOS_OFF + pos] = 1.0f/(1.0f + expf(OUT[120][b]));
  }
}

extern "C" void kernel_launch(void* const* d_in, const int* in_sizes, int n_in,
                              void* d_out, int out_size, void* d_ws, size_t ws_size,
                              hipStream_t stream){
  (void)in_sizes; (void)n_in; (void)out_size; (void)ws_size;
  const float* strokes = (const float*)d_in[0];
  const float* onehots = (const float*)d_in[1];
  const float* tmask   = (const float*)d_in[2];
  const float* Wih1    = (const float*)d_in[3];
  const float* Whh1    = (const float*)d_in[4];
  const float* b1      = (const float*)d_in[5];
  const float* Wwin    = (const float*)d_in[6];
  const float* bwin    = (const float*)d_in[7];
  const float* Wih2    = (const float*)d_in[8];
  const float* Whh2    = (const float*)d_in[9];
  const float* b2      = (const float*)d_in[10];
  const float* Wfc     = (const float*)d_in[11];
  const float* bfc     = (const float*)d_in[12];

  float* ws    = (float*)d_ws;
  float* outp  = (float*)d_out;
  float* H1t   = ws + WS_H1T;
  float* H2t   = ws + WS_H2T;
  float* Wh    = ws + WS_WHT;
  float* XST   = ws + WS_XST;
  float* WALL1 = ws + WS_WALL1;
  float* WALL2 = ws + WS_WALL2;
  float* WfcT  = ws + WS_WFCT;
  int*   cnts  = (int*)(ws + WS_CNT);

  hipLaunchKernelGGL(prep_init, dim3((TT*3*64 + 255)/256), dim3(256), 0, stream,
                     onehots, strokes, H1t, H2t, Wh, XST, cnts);
  hipLaunchKernelGGL(prep_wall, dim3((2121600 + 255)/256), dim3(256), 0, stream,
                     Wih1, Whh1, Wih2, Whh2, WALL1, WALL2);
  hipLaunchKernelGGL(prep_wfc, dim3((FCIN*FCOUT + 255)/256), dim3(256), 0, stream,
                     Wfc, WfcT);

  hipLaunchKernelGGL(recurrent_kernel, dim3(TOTB), dim3(THR), 0, stream,
                     Wwin, bwin, b1, b2, tmask, onehots, WALL1, WALL2,
                     H1t, H2t, Wh, XST, cnts, outp);

  hipLaunchKernelGGL(fc2_kernel, dim3(TT), dim3(128), 0, stream,
                     H1t, H2t, WfcT, bfc, outp);
}